// Round 4
// baseline (280.068 us; speedup 1.0000x reference)
//
#include <hip/hip_runtime.h>
#include <hip/hip_cooperative_groups.h>
#include <math.h>

// Problem constants
#define BB 16
#define CC 512
#define HW 784
#define RR 32
#define NHD 8
#define HD 64
#define NT 784
#define NTILE 49                       // 784 = 49 * 16 n-tiles
#define CBS 132                        // Cb stride: writes 2-way (S%8==4), b128 reads uniform

// workspace layout (float offsets)
#define OFS_AVGP   0
#define OFS_MAXP   8192
#define OFS_CHS    16384
#define OFS_SP     49664
#define OFS_P1     62208
#define OFS_ABAR   70400
#define OFS_XG     78592
#define XG_SZ      (BB*CC*HW)          // 6,422,528 floats (region reused below)
#define OFS_XGT    (OFS_XG + XG_SZ)            // bf16 frag xg^T  (XG_SZ bf16)
#define OFS_QBF    (OFS_XGT + XG_SZ/2)         // bf16 frag Q     (XG_SZ bf16)
#define OFS_KBF    (OFS_QBF + XG_SZ/2)         // bf16 frag K     (XG_SZ bf16)
#define OFS_V2     (OFS_KBF + XG_SZ/2)         // bf16 V [bh][n][d]
#define OFS_WF     (OFS_V2 + XG_SZ)            // bf16 frag weights (786432 bf16)
// overlays inside the dead xg region:
#define OFS_W      OFS_XG                      // wsum   (100352 floats)
#define OFS_PV     (OFS_XG + 131072)           // pv     (8192)
#define OFS_CMAXP  (OFS_XG + 262144)           // partial cmax [16][16][784]
#define OFS_CMEANP (OFS_CMAXP + 200704)        // partial csum [16][16][784]

typedef __attribute__((ext_vector_type(8))) short bf16x8;
typedef __attribute__((ext_vector_type(4))) float f32x4;

__device__ __forceinline__ unsigned short f2bf(float x) {
  union { float f; unsigned u; } v; v.f = x;
  unsigned r = v.u + 0x7fffu + ((v.u >> 16) & 1u);
  return (unsigned short)(r >> 16);
}
__device__ __forceinline__ float bf2f(unsigned short x) {
  union { unsigned u; float f; } v; v.u = ((unsigned)x) << 16;
  return v.f;
}
// async global->LDS, 16 B per lane; lds base must be wave-uniform (lane scatters x16B)
__device__ __forceinline__ void async16(const unsigned short* g, unsigned short* l) {
  __builtin_amdgcn_global_load_lds(
      (const __attribute__((address_space(1))) unsigned int*)g,
      (__attribute__((address_space(3))) unsigned int*)l, 16, 0, 0);
}

struct MegaArgs {
  const float *x, *mlp_w1, *mlp_b1, *mlp_w2, *mlp_b2;
  const float *sp_w, *sp_g, *sp_bb, *sp_mu, *sp_var;
  const float *wq, *bq, *wk, *bk, *wv, *bv, *wo, *bo;
  const float *ln_g, *ln_b, *fc1_w, *fc1_b, *fc2_w, *fc2_b;
  float *avg_p, *max_p, *chs, *sp, *p1, *abar, *wsum, *pv, *out;
  float *cmaxp, *cmeanp;
  unsigned short *xgT, *Qbf, *Kbf, *Vbf, *Wf;
};

// =============== MEGA: entire pipeline, one cooperative kernel ===============
// Phase bodies verbatim from the round-3-verified kernels; indices re-derived
// as grid-stride loops. __syncthreads() guards added where LDS is reused
// across loop iterations. 9 grid.sync()s replace 9 kernel boundaries.
__global__ __launch_bounds__(256) void k_mega(MegaArgs A) {
  __shared__ __align__(16) unsigned char smem[65536];
  cooperative_groups::grid_group gg = cooperative_groups::this_grid();
  const int bid = blockIdx.x, gdim = gridDim.x;
  const int t = threadIdx.x, w = t >> 6, ln = t & 63;

  // ---- P0: per-(b,c) avg+max pool  |  wfrag  |  zero wsum/p1/out ----------
  for (int wk = bid; wk < 2048; wk += gdim) {
    int row = wk*4 + w;
    const float* xr = A.x + (size_t)row * HW;
    float s = 0.f, m = -INFINITY;
    for (int i = ln; i < HW; i += 64) { float v = xr[i]; s += v; m = fmaxf(m, v); }
    for (int o = 32; o; o >>= 1) { s += __shfl_down(s, o, 64); m = fmaxf(m, __shfl_down(m, o, 64)); }
    if (ln == 0) { A.avg_p[row] = s * (1.f/HW); A.max_p[row] = m; }
  }
  for (int wk = bid; wk < 384; wk += gdim) {
    int idx = wk*256 + t;
    int l2 = idx & 63;
    int s  = (idx >> 6) & 15;
    int ct = (idx >> 10) & 31;
    int mat = idx >> 15;
    const float* W = (mat==0)? A.wq : (mat==1)? A.wk : A.wv;
    const float* src = W + (size_t)(ct*16 + (l2 & 15))*CC + s*32 + (l2 >> 4)*8;
    float4 f0 = *(const float4*)src;
    float4 f1 = *(const float4*)(src + 4);
    bf16x8 p;
    p[0]=(short)f2bf(f0.x); p[1]=(short)f2bf(f0.y); p[2]=(short)f2bf(f0.z); p[3]=(short)f2bf(f0.w);
    p[4]=(short)f2bf(f1.x); p[5]=(short)f2bf(f1.y); p[6]=(short)f2bf(f1.z); p[7]=(short)f2bf(f1.w);
    *(bf16x8*)(A.Wf + (size_t)idx*8) = p;
  }
  {
    const float4 z = {0.f,0.f,0.f,0.f};
    for (int i = bid*256 + t; i < 27136; i += gdim*256) {
      if (i < 25088) *(float4*)&A.wsum[(size_t)i*4] = z;
      else           *(float4*)&A.p1[(size_t)(i-25088)*4] = z;
    }
    if (bid == 0 && t < BB) A.out[t] = 0.f;
  }
  gg.sync();

  // ---- P1: channel-gate MLP (16 works) -------------------------------------
  {
    float* pa = (float*)smem; float* pm = pa + CC; float* part = pm + CC; float* hr = part + 256;
    for (int wk = bid; wk < 16; wk += gdim) {
      int b = wk;
      for (int i = t; i < CC; i += 256) { pa[i] = A.avg_p[b*CC+i]; pm[i] = A.max_p[b*CC+i]; }
      __syncthreads();
      {
        int rp = t & 63, ch = t >> 6;
        int r = rp & 31;
        const float* src = (rp < 32) ? pa : pm;
        const float* wr = A.mlp_w1 + (size_t)r*CC + ch*128;
        float s = 0.f;
        #pragma unroll 8
        for (int c = 0; c < 128; c++) s += src[ch*128 + c] * wr[c];
        part[t] = s;
      }
      __syncthreads();
      if (t < 64)
        hr[t] = fmaxf(part[t] + part[64+t] + part[128+t] + part[192+t] + A.mlp_b1[t & 31], 0.f);
      __syncthreads();
      for (int c = t; c < CC; c += 256) {
        float a = 2.f*A.mlp_b2[c];
        const float* wr = A.mlp_w2 + c*RR;
        #pragma unroll
        for (int r = 0; r < RR; r++) a += (hr[r]+hr[32+r])*wr[r];
        A.chs[b*CC+c] = 1.f/(1.f+__expf(-a));
      }
      __syncthreads();
    }
  }
  gg.sync();

  // ---- P2: channel-gate partials (512 works = (b,cg) x pixel-half) ---------
  {
    float* cs = (float*)smem;
    for (int wk = bid; wk < 512; wk += gdim) {
      int pr = wk >> 1, half = wk & 1;
      int b = pr & 15, cg = pr >> 4;
      if (t < 32) cs[t] = A.chs[b*CC + cg*32 + t];
      __syncthreads();
      const float* xb = A.x + ((size_t)b*CC + cg*32)*HW;
      for (int pix = half*392 + t; pix < half*392 + 392; pix += 256) {
        float mx = -INFINITY, sm = 0.f;
        #pragma unroll
        for (int c = 0; c < 32; c++) {
          float v = xb[(size_t)c*HW + pix] * cs[c];
          mx = fmaxf(mx, v); sm += v;
        }
        A.cmaxp[(size_t)(cg*BB + b)*HW + pix] = mx;
        A.cmeanp[(size_t)(cg*BB + b)*HW + pix] = sm;
      }
      __syncthreads();
    }
  }
  gg.sync();

  // ---- P3: reduce partials -> 7x7 conv + BN + sigmoid (64 works) -----------
  {
    float* cmx = (float*)smem; float* cmn = cmx + HW;
    for (int wk = bid; wk < 64; wk += gdim) {
      int b = wk & 15, q = wk >> 4;
      for (int pix = t; pix < HW; pix += 256) {
        float mx = -INFINITY, sm = 0.f;
        #pragma unroll
        for (int cg = 0; cg < 16; cg++) {
          mx = fmaxf(mx, A.cmaxp[(size_t)(cg*BB + b)*HW + pix]);
          sm += A.cmeanp[(size_t)(cg*BB + b)*HW + pix];
        }
        cmx[pix] = mx; cmn[pix] = sm * (1.f/CC);
      }
      __syncthreads();
      if (t < 196) {
        int pix = q*196 + t;
        float bnscale = rsqrtf(A.sp_var[0]+1e-5f)*A.sp_g[0];
        int h = pix/28, wd = pix%28;
        float acc = 0.f;
        for (int kh = 0; kh < 7; kh++) {
          int ih = h + kh - 3; if (ih < 0 || ih >= 28) continue;
          for (int kw = 0; kw < 7; kw++) {
            int iw = wd + kw - 3; if (iw < 0 || iw >= 28) continue;
            int ip = ih*28+iw;
            acc += cmx[ip]*A.sp_w[kh*7+kw] + cmn[ip]*A.sp_w[49+kh*7+kw];
          }
        }
        float s = (acc - A.sp_mu[0])*bnscale + A.sp_bb[0];
        A.sp[b*HW+pix] = 1.f/(1.f+__expf(-s));
      }
      __syncthreads();
    }
  }
  gg.sync();

  // ---- P4: fused gates -> bf16 xgT + p1 partial sums (784 works) -----------
  {
    float* cs = (float*)smem;
    for (int wk = bid; wk < 784; wk += gdim) {
      int nt = wk % 49, b = wk / 49;
      for (int i = t; i < CC; i += 256) cs[i] = A.chs[b*CC+i];
      __syncthreads();
      int n = nt*16 + (ln & 15);
      float spv = A.sp[b*HW + n];
      const float* xb = A.x + (size_t)b*CC*HW;
      #pragma unroll
      for (int i = 0; i < 4; i++) {
        int s = (t >> 6) + 4*i;
        int c = s*32 + (ln >> 4)*8;
        float vf[8];
        bf16x8 p;
        #pragma unroll
        for (int j = 0; j < 8; j++) {
          vf[j] = xb[(size_t)(c+j)*HW + n] * cs[c+j] * spv;
          p[j] = (short)f2bf(vf[j]);
        }
        *(bf16x8*)(A.xgT + ((((size_t)b*NTILE + nt)*16 + s)*64 + ln)*8) = p;
        #pragma unroll
        for (int j = 0; j < 8; j++) {
          float v = vf[j];
          v += __shfl_xor(v,1,64); v += __shfl_xor(v,2,64);
          v += __shfl_xor(v,4,64); v += __shfl_xor(v,8,64);
          vf[j] = v;
        }
        if ((ln & 15) == 0) {
          #pragma unroll
          for (int j = 0; j < 8; j++) atomicAdd(&A.p1[b*CC + c + j], vf[j]);
        }
      }
      __syncthreads();
    }
  }
  gg.sync();

  // ---- P5: QKV projection MFMA (1248 works) --------------------------------
  {
    unsigned short* Alds = (unsigned short*)smem;
    float* Cb = (float*)smem;
    for (int blk = bid; blk < 1248; blk += gdim) {
      __syncthreads();                            // LDS reuse guard across works
      int yb = blk / 208;
      int r0 = blk % 208;
      int mt = r0 >> 4;
      int b  = r0 & 15;
      int mat = yb >> 1;
      int c0 = (yb & 1) * 256;
      const unsigned short* Ab = A.xgT + (size_t)b*NTILE*8192;
      const unsigned short* Bb = A.Wf + (size_t)mat*32*8192;
      int ctgb = (c0 >> 4) + w*2;
      int ntc[4];
      #pragma unroll
      for (int m = 0; m < 4; m++) { int nt = 4*mt + m; ntc[m] = (nt > 48) ? 48 : nt; }
      #pragma unroll
      for (int j0 = 0; j0 < 16; j0++) {
        int j = w + 4*j0;
        int m = j >> 4, sj = j & 15;
        async16(Ab + (size_t)ntc[m]*8192 + (size_t)(sj*64 + ln)*8,
                Alds + (size_t)j*512);
      }
      f32x4 acc[4][4];
      #pragma unroll
      for (int m = 0; m < 4; m++)
        #pragma unroll
        for (int c2 = 0; c2 < 4; c2++) acc[m][c2] = (f32x4){0.f,0.f,0.f,0.f};
      __syncthreads();                            // drain staging + barrier
      #pragma unroll 2
      for (int s = 0; s < 16; s++) {
        bf16x8 bf[4];
        bf[0] = *(const bf16x8*)(Bb + (size_t)((ctgb  )*16 + s)*512 + ln*8);
        bf[1] = *(const bf16x8*)(Bb + (size_t)((ctgb+1)*16 + s)*512 + ln*8);
        bf[2] = *(const bf16x8*)(Bb + (size_t)((ctgb+8)*16 + s)*512 + ln*8);
        bf[3] = *(const bf16x8*)(Bb + (size_t)((ctgb+9)*16 + s)*512 + ln*8);
        bf16x8 af[4];
        #pragma unroll
        for (int m = 0; m < 4; m++)
          af[m] = *(const bf16x8*)(Alds + (size_t)(m*16 + s)*512 + ln*8);
        #pragma unroll
        for (int m = 0; m < 4; m++) {
          #pragma unroll
          for (int c2 = 0; c2 < 4; c2++)
            acc[m][c2] = __builtin_amdgcn_mfma_f32_16x16x32_bf16(af[m], bf[c2], acc[m][c2], 0,0,0);
        }
      }
      __syncthreads();                            // A reads done; reuse LDS as Cb
      const float* bias = (mat==0)? A.bq : (mat==1)? A.bk : A.bv;
      #pragma unroll
      for (int ch = 0; ch < 2; ch++) {
        if (ch) __syncthreads();
        #pragma unroll
        for (int m = 0; m < 4; m++)
          #pragma unroll
          for (int c2 = 0; c2 < 2; c2++)
            #pragma unroll
            for (int r = 0; r < 4; r++)
              Cb[(m*16 + (ln>>4)*4 + r)*CBS + w*32 + c2*16 + (ln&15)] = acc[m][ch*2+c2][r];
        __syncthreads();
        #pragma unroll
        for (int i = 0; i < 4; i++) {
          int p = w*4 + i;
          int ntl = p >> 2, sl = p & 3;
          int nt = 4*mt + ntl;
          if (nt > 48) continue;
          int row = ntl*16 + (ln & 15);
          int col = sl*32 + (ln >> 4)*8;
          float4 v0 = *(const float4*)&Cb[row*CBS + col];
          float4 v1 = *(const float4*)&Cb[row*CBS + col + 4];
          float v[8] = {v0.x, v0.y, v0.z, v0.w, v1.x, v1.y, v1.z, v1.w};
          int colA = ch*128 + col;
          #pragma unroll
          for (int j = 0; j < 8; j++) v[j] += bias[c0 + colA + j];
          int token = nt*16 + (ln & 15);
          int h = (c0 >> 6) + (ch << 1) + (sl >> 1);
          int bh = b*NHD + h;
          bf16x8 pk;
          #pragma unroll
          for (int j = 0; j < 8; j++) pk[j] = (short)f2bf(v[j]);
          if (mat < 2) {
            unsigned short* Out = (mat == 0) ? A.Qbf : A.Kbf;
            *(bf16x8*)(Out + ((size_t)bh*NTILE + nt)*1024 + (size_t)(sl & 1)*512 + ln*8) = pk;
          } else {
            int d = (sl & 1)*32 + (ln >> 4)*8;
            *(bf16x8*)(A.Vbf + ((size_t)bh*NT + token)*HD + d) = pk;
          }
        }
      }
    }
  }
  gg.sync();

  // ---- P6: MFMA attention, 2 q-tiles per work (3200 works) -----------------
  {
    float* lt  = (float*)smem;                    // [2][64]
    float* rlp = lt + 128;                        // [2][16]
    for (int wk = bid; wk < 3200; wk += gdim) {
      int bh = wk & 127, pg = wk >> 7;
      int ntA = pg*2;
      bool hasB = (ntA + 1) < NTILE;
      int ntB = hasB ? (ntA + 1) : ntA;
      const unsigned short* QbA = A.Qbf + ((size_t)bh*NTILE + ntA)*1024;
      const unsigned short* QbB = A.Qbf + ((size_t)bh*NTILE + ntB)*1024;
      const unsigned short* Kb = A.Kbf + (size_t)bh*NTILE*1024;
      bf16x8 qA0 = *(const bf16x8*)(QbA + ln*8);
      bf16x8 qA1 = *(const bf16x8*)(QbA + 512 + ln*8);
      bf16x8 qB0 = *(const bf16x8*)(QbB + ln*8);
      bf16x8 qB1 = *(const bf16x8*)(QbB + 512 + ln*8);
      f32x4 evA[13], evB[13];
      float lpA[4] = {0.f,0.f,0.f,0.f}, lpB[4] = {0.f,0.f,0.f,0.f};
      #pragma unroll
      for (int i = 0; i < 13; i++) {
        int mt = w + 4*i;
        bool valid = (i < 12) || (w == 0);
        int mtc = valid ? mt : 48;
        bf16x8 k0 = *(const bf16x8*)(Kb + (size_t)mtc*1024 + ln*8);
        bf16x8 k1 = *(const bf16x8*)(Kb + (size_t)mtc*1024 + 512 + ln*8);
        f32x4 a = {0.f,0.f,0.f,0.f};
        a = __builtin_amdgcn_mfma_f32_16x16x32_bf16(qA0, k0, a, 0,0,0);
        a = __builtin_amdgcn_mfma_f32_16x16x32_bf16(qA1, k1, a, 0,0,0);
        f32x4 c = {0.f,0.f,0.f,0.f};
        c = __builtin_amdgcn_mfma_f32_16x16x32_bf16(qB0, k0, c, 0,0,0);
        c = __builtin_amdgcn_mfma_f32_16x16x32_bf16(qB1, k1, c, 0,0,0);
        f32x4 ea, eb;
        #pragma unroll
        for (int r = 0; r < 4; r++) {
          ea[r] = __expf(a[r]*0.125f);
          eb[r] = __expf(c[r]*0.125f);
        }
        evA[i] = ea; evB[i] = eb;
        if (valid) {
          #pragma unroll
          for (int r = 0; r < 4; r++) { lpA[r] += ea[r]; lpB[r] += eb[r]; }
        }
      }
      #pragma unroll
      for (int r = 0; r < 4; r++) {
        float v = lpA[r];
        v += __shfl_xor(v,1,64); v += __shfl_xor(v,2,64);
        v += __shfl_xor(v,4,64); v += __shfl_xor(v,8,64);
        if ((ln & 15) == 0) lt[w*16 + (ln>>4)*4 + r] = v;
        float u = lpB[r];
        u += __shfl_xor(u,1,64); u += __shfl_xor(u,2,64);
        u += __shfl_xor(u,4,64); u += __shfl_xor(u,8,64);
        if ((ln & 15) == 0) lt[64 + w*16 + (ln>>4)*4 + r] = u;
      }
      __syncthreads();
      if (t < 32) {
        int g = t >> 4, q = t & 15;
        rlp[g*16 + q] = 1.f / (lt[g*64+q] + lt[g*64+16+q] + lt[g*64+32+q] + lt[g*64+48+q]);
      }
      __syncthreads();
      f32x4 rlA = *(const f32x4*)&rlp[(ln >> 4)*4];
      f32x4 rlB = *(const f32x4*)&rlp[16 + (ln >> 4)*4];
      #pragma unroll
      for (int i = 0; i < 13; i++) {
        int mt = w + 4*i;
        bool valid = (i < 12) || (w == 0);
        float v = evA[i][0]*rlA[0] + evA[i][1]*rlA[1] + evA[i][2]*rlA[2] + evA[i][3]*rlA[3];
        if (hasB)
          v += evB[i][0]*rlB[0] + evB[i][1]*rlB[1] + evB[i][2]*rlB[2] + evB[i][3]*rlB[3];
        v += __shfl_xor(v, 16, 64);
        v += __shfl_xor(v, 32, 64);
        if (valid && ln < 16)
          atomicAdd(&A.wsum[bh*NT + mt*16 + ln], v);
      }
    }
  }
  gg.sync();

  // ---- P7: abar = (1/N) wsum @ V (128 works) -------------------------------
  {
    float* red = (float*)smem;
    for (int wk = bid; wk < 128; wk += gdim) {
      int bh = wk;
      int d = t & 63, chunk = t >> 6;
      float acc = 0.f;
      const unsigned short* vb = A.Vbf + (size_t)bh*NT*HD;
      const float* wb = A.wsum + bh*NT;
      for (int m = chunk*196; m < (chunk+1)*196; m++)
        acc += wb[m] * bf2f(vb[(size_t)m*HD + d]);
      red[t] = acc;
      __syncthreads();
      if (t < 64)
        A.abar[bh*HD + t] = (red[t] + red[64+t] + red[128+t] + red[192+t]) * (1.f/NT);
      __syncthreads();
    }
  }
  gg.sync();

  // ---- P8: pv = bo + p1/HW + abar @ wo^T (256 works) -----------------------
  for (int wk = bid; wk < 256; wk += gdim) {
    int b = wk & 15, cg = wk >> 4;
    float a[8];
    #pragma unroll
    for (int k = 0; k < 8; k++) a[k] = A.abar[b*CC + ln + 64*k];
    int c0 = cg*32 + w*8;
    for (int i = 0; i < 8; i++) {
      int c = c0 + i;
      const float* wr = A.wo + (size_t)c*CC;
      float s = 0.f;
      #pragma unroll
      for (int k = 0; k < 8; k++) s += a[k] * wr[ln + 64*k];
      for (int o = 32; o; o >>= 1) s += __shfl_down(s, o, 64);
      if (ln == 0) A.pv[b*CC + c] = s + A.bo[c] + A.p1[b*CC + c] * (1.f/HW);
    }
  }
  gg.sync();

  // ---- P9: LN + fc1 + ReLU + fc2 -> out (256 works) ------------------------
  for (int wk = bid; wk < 256; wk += gdim) {
    int b = wk & 15, cg = wk >> 4;
    float a[8];
    float s = 0.f, s2 = 0.f;
    #pragma unroll
    for (int k = 0; k < 8; k++) {
      a[k] = A.pv[b*CC + ln + 64*k];
      s += a[k]; s2 += a[k]*a[k];
    }
    for (int o = 32; o; o >>= 1) { s += __shfl_down(s, o, 64); s2 += __shfl_down(s2, o, 64); }
    s = __shfl(s, 0, 64); s2 = __shfl(s2, 0, 64);
    float mean = s * (1.f/CC);
    float rs = rsqrtf(s2*(1.f/CC) - mean*mean + 1e-5f);
    #pragma unroll
    for (int k = 0; k < 8; k++)
      a[k] = (a[k]-mean)*rs*A.ln_g[ln + 64*k] + A.ln_b[ln + 64*k];
    int c0 = cg*32 + w*8;
    float o2 = 0.f;
    for (int i = 0; i < 8; i++) {
      int c = c0 + i;
      const float* wr = A.fc1_w + (size_t)c*CC;
      float v = 0.f;
      #pragma unroll
      for (int k = 0; k < 8; k++) v += a[k] * wr[ln + 64*k];
      for (int o = 32; o; o >>= 1) v += __shfl_down(v, o, 64);
      if (ln == 0) o2 += fmaxf(v + A.fc1_b[c], 0.f) * A.fc2_w[c];
    }
    if (ln == 0) {
      if (cg == 0 && w == 0) o2 += A.fc2_b[0];
      atomicAdd(&A.out[b], o2);
    }
  }
}

// =================== FALLBACK: verified round-3 pipeline ====================
__global__ void k_pre(const float* __restrict__ x,
                      const float* __restrict__ wq, const float* __restrict__ wk,
                      const float* __restrict__ wv,
                      float* avg_p, float* max_p, unsigned short* __restrict__ Wf,
                      float* __restrict__ wsum, float* __restrict__ p1,
                      float* __restrict__ outp) {
  int bid = blockIdx.x;
  if (bid < 2048) {
    int wid = threadIdx.x >> 6;
    int lane = threadIdx.x & 63;
    int row = bid * 4 + wid;
    const float* xr = x + (size_t)row * HW;
    float s = 0.f, m = -INFINITY;
    for (int i = lane; i < HW; i += 64) { float v = xr[i]; s += v; m = fmaxf(m, v); }
    for (int o = 32; o; o >>= 1) { s += __shfl_down(s, o, 64); m = fmaxf(m, __shfl_down(m, o, 64)); }
    if (lane == 0) { avg_p[row] = s * (1.f/HW); max_p[row] = m; }
  } else if (bid < 2432) {
    int idx = (bid - 2048)*256 + threadIdx.x;
    int ln = idx & 63;
    int s  = (idx >> 6) & 15;
    int ct = (idx >> 10) & 31;
    int mat = idx >> 15;
    const float* W = (mat==0)? wq : (mat==1)? wk : wv;
    const float* src = W + (size_t)(ct*16 + (ln & 15))*CC + s*32 + (ln >> 4)*8;
    float4 f0 = *(const float4*)src;
    float4 f1 = *(const float4*)(src + 4);
    bf16x8 p;
    p[0]=(short)f2bf(f0.x); p[1]=(short)f2bf(f0.y); p[2]=(short)f2bf(f0.z); p[3]=(short)f2bf(f0.w);
    p[4]=(short)f2bf(f1.x); p[5]=(short)f2bf(f1.y); p[6]=(short)f2bf(f1.z); p[7]=(short)f2bf(f1.w);
    *(bf16x8*)(Wf + (size_t)idx*8) = p;
  } else {
    int idx = (bid - 2432)*256 + threadIdx.x;
    const float4 z = {0.f,0.f,0.f,0.f};
    if (idx < 4) *(float4*)&outp[idx*4] = z;
    for (int i = idx; i < 27136; i += 16384) {
      if (i < 25088) *(float4*)&wsum[(size_t)i*4] = z;
      else           *(float4*)&p1[(size_t)(i-25088)*4] = z;
    }
  }
}

__global__ void k_chmlp(const float* avg_p, const float* max_p,
                        const float* w1, const float* b1,
                        const float* w2, const float* b2, float* chs) {
  __shared__ float pa[CC], pm[CC], part[256], hr[64];
  int b = blockIdx.x, t = threadIdx.x;
  for (int i = t; i < CC; i += 256) { pa[i] = avg_p[b*CC+i]; pm[i] = max_p[b*CC+i]; }
  __syncthreads();
  {
    int rp = t & 63, ch = t >> 6;
    int r = rp & 31;
    const float* src = (rp < 32) ? pa : pm;
    const float* wr = w1 + (size_t)r*CC + ch*128;
    float s = 0.f;
    #pragma unroll 8
    for (int c = 0; c < 128; c++) s += src[ch*128 + c] * wr[c];
    part[t] = s;
  }
  __syncthreads();
  if (t < 64)
    hr[t] = fmaxf(part[t] + part[64+t] + part[128+t] + part[192+t] + b1[t & 31], 0.f);
  __syncthreads();
  for (int c = t; c < CC; c += 256) {
    float a = 2.f*b2[c];
    const float* wr = w2 + c*RR;
    #pragma unroll
    for (int r = 0; r < RR; r++) a += (hr[r]+hr[32+r])*wr[r];
    chs[b*CC+c] = 1.f/(1.f+__expf(-a));
  }
}

__global__ void k_chgatep(const float* __restrict__ x, const float* __restrict__ chs,
                          float* __restrict__ cmaxp, float* __restrict__ cmeanp) {
  __shared__ float cs[32];
  int b = blockIdx.x, cg = blockIdx.y, t = threadIdx.x;
  if (t < 32) cs[t] = chs[b*CC + cg*32 + t];
  __syncthreads();
  const float* xb = x + ((size_t)b*CC + cg*32)*HW;
  for (int pix = t; pix < HW; pix += 256) {
    float mx = -INFINITY, sm = 0.f;
    #pragma unroll
    for (int c = 0; c < 32; c++) {
      float v = xb[(size_t)c*HW + pix] * cs[c];
      mx = fmaxf(mx, v); sm += v;
    }
    cmaxp[(size_t)(cg*BB + b)*HW + pix] = mx;
    cmeanp[(size_t)(cg*BB + b)*HW + pix] = sm;
  }
}

__global__ void k_credsp(const float* __restrict__ cmaxp, const float* __restrict__ cmeanp,
                         const float* __restrict__ w, const float* g, const float* be,
                         const float* mu, const float* var, float* __restrict__ sp) {
  __shared__ float cmx[HW], cmn[HW];
  int b = blockIdx.x, q = blockIdx.y, t = threadIdx.x;
  for (int pix = t; pix < HW; pix += 256) {
    float mx = -INFINITY, sm = 0.f;
    #pragma unroll
    for (int cg = 0; cg < 16; cg++) {
      mx = fmaxf(mx, cmaxp[(size_t)(cg*BB + b)*HW + pix]);
      sm += cmeanp[(size_t)(cg*BB + b)*HW + pix];
    }
    cmx[pix] = mx; cmn[pix] = sm * (1.f/CC);
  }
  __syncthreads();
  if (t < 196) {
    int pix = q*196 + t;
    float bnscale = rsqrtf(var[0]+1e-5f)*g[0];
    int h = pix/28, wd = pix%28;
    float acc = 0.f;
    for (int kh = 0; kh < 7; kh++) {
      int ih = h + kh - 3; if (ih < 0 || ih >= 28) continue;
      for (int kw = 0; kw < 7; kw++) {
        int iw = wd + kw - 3; if (iw < 0 || iw >= 28) continue;
        int ip = ih*28+iw;
        acc += cmx[ip]*w[kh*7+kw] + cmn[ip]*w[49+kh*7+kw];
      }
    }
    float s = (acc - mu[0])*bnscale + be[0];
    sp[b*HW+pix] = 1.f/(1.f+__expf(-s));
  }
}

__global__ void k_sfuse(const float* __restrict__ x, const float* __restrict__ chs,
                        const float* __restrict__ sp, unsigned short* __restrict__ xgT,
                        float* __restrict__ p1) {
  __shared__ float cs[CC];
  int nt = blockIdx.x, b = blockIdx.y;
  int t = threadIdx.x, ln = t & 63;
  for (int i = t; i < CC; i += 256) cs[i] = chs[b*CC+i];
  __syncthreads();
  int n = nt*16 + (ln & 15);
  float spv = sp[b*HW + n];
  const float* xb = x + (size_t)b*CC*HW;
  #pragma unroll
  for (int i = 0; i < 4; i++) {
    int s = (t >> 6) + 4*i;
    int c = s*32 + (ln >> 4)*8;
    float vf[8];
    bf16x8 p;
    #pragma unroll
    for (int j = 0; j < 8; j++) {
      vf[j] = xb[(size_t)(c+j)*HW + n] * cs[c+j] * spv;
      p[j] = (short)f2bf(vf[j]);
    }
    *(bf16x8*)(xgT + ((((size_t)b*NTILE + nt)*16 + s)*64 + ln)*8) = p;
    #pragma unroll
    for (int j = 0; j < 8; j++) {
      float v = vf[j];
      v += __shfl_xor(v,1,64); v += __shfl_xor(v,2,64);
      v += __shfl_xor(v,4,64); v += __shfl_xor(v,8,64);
      vf[j] = v;
    }
    if ((ln & 15) == 0) {
      #pragma unroll
      for (int j = 0; j < 8; j++) atomicAdd(&p1[b*CC + c + j], vf[j]);
    }
  }
}

__global__ __launch_bounds__(256) void k_qkv_mfma(
    const unsigned short* __restrict__ xgT, const unsigned short* __restrict__ Wf,
    const float* __restrict__ bq, const float* __restrict__ bk, const float* __restrict__ bv,
    unsigned short* __restrict__ Qbf, unsigned short* __restrict__ Kbf,
    unsigned short* __restrict__ Vbf) {
  __shared__ __align__(16) unsigned char smem[65536];
  unsigned short* Alds = (unsigned short*)smem;
  float* Cb = (float*)smem;
  int blk = blockIdx.x;
  int yb = blk / 208;
  int r0 = blk % 208;
  int mt = r0 >> 4;
  int b  = r0 & 15;
  int mat = yb >> 1;
  int c0 = (yb & 1) * 256;
  int t = threadIdx.x, w = t >> 6, ln = t & 63;
  const unsigned short* Ab = xgT + (size_t)b*NTILE*8192;
  const unsigned short* Bb = Wf + (size_t)mat*32*8192;
  int ctgb = (c0 >> 4) + w*2;
  int ntc[4];
  #pragma unroll
  for (int m = 0; m < 4; m++) { int nt = 4*mt + m; ntc[m] = (nt > 48) ? 48 : nt; }
  #pragma unroll
  for (int j0 = 0; j0 < 16; j0++) {
    int j = w + 4*j0;
    int m = j >> 4, sj = j & 15;
    async16(Ab + (size_t)ntc[m]*8192 + (size_t)(sj*64 + ln)*8,
            Alds + (size_t)j*512);
  }
  f32x4 acc[4][4];
  #pragma unroll
  for (int m = 0; m < 4; m++)
    #pragma unroll
    for (int c2 = 0; c2 < 4; c2++) acc[m][c2] = (f32x4){0.f,0.f,0.f,0.f};
  __syncthreads();
  #pragma unroll 2
  for (int s = 0; s < 16; s++) {
    bf16x8 bf[4];
    bf[0] = *(const bf16x8*)(Bb + (size_t)((ctgb  )*16 + s)*512 + ln*8);
    bf[1] = *(const bf16x8*)(Bb + (size_t)((ctgb+1)*16 + s)*512 + ln*8);
    bf[2] = *(const bf16x8*)(Bb + (size_t)((ctgb+8)*16 + s)*512 + ln*8);
    bf[3] = *(const bf16x8*)(Bb + (size_t)((ctgb+9)*16 + s)*512 + ln*8);
    bf16x8 af[4];
    #pragma unroll
    for (int m = 0; m < 4; m++)
      af[m] = *(const bf16x8*)(Alds + (size_t)(m*16 + s)*512 + ln*8);
    #pragma unroll
    for (int m = 0; m < 4; m++) {
      #pragma unroll
      for (int c2 = 0; c2 < 4; c2++)
        acc[m][c2] = __builtin_amdgcn_mfma_f32_16x16x32_bf16(af[m], bf[c2], acc[m][c2], 0,0,0);
    }
  }
  __syncthreads();
  const float* bias = (mat==0)? bq : (mat==1)? bk : bv;
  #pragma unroll
  for (int ch = 0; ch < 2; ch++) {
    if (ch) __syncthreads();
    #pragma unroll
    for (int m = 0; m < 4; m++)
      #pragma unroll
      for (int c2 = 0; c2 < 2; c2++)
        #pragma unroll
        for (int r = 0; r < 4; r++)
          Cb[(m*16 + (ln>>4)*4 + r)*CBS + w*32 + c2*16 + (ln&15)] = acc[m][ch*2+c2][r];
    __syncthreads();
    #pragma unroll
    for (int i = 0; i < 4; i++) {
      int p = w*4 + i;
      int ntl = p >> 2, sl = p & 3;
      int nt = 4*mt + ntl;
      if (nt > 48) continue;
      int row = ntl*16 + (ln & 15);
      int col = sl*32 + (ln >> 4)*8;
      float4 v0 = *(const float4*)&Cb[row*CBS + col];
      float4 v1 = *(const float4*)&Cb[row*CBS + col + 4];
      float v[8] = {v0.x, v0.y, v0.z, v0.w, v1.x, v1.y, v1.z, v1.w};
      int colA = ch*128 + col;
      #pragma unroll
      for (int j = 0; j < 8; j++) v[j] += bias[c0 + colA + j];
      int token = nt*16 + (ln & 15);
      int h = (c0 >> 6) + (ch << 1) + (sl >> 1);
      int bh = b*NHD + h;
      bf16x8 pk;
      #pragma unroll
      for (int j = 0; j < 8; j++) pk[j] = (short)f2bf(v[j]);
      if (mat < 2) {
        unsigned short* Out = (mat == 0) ? Qbf : Kbf;
        *(bf16x8*)(Out + ((size_t)bh*NTILE + nt)*1024 + (size_t)(sl & 1)*512 + ln*8) = pk;
      } else {
        int d = (sl & 1)*32 + (ln >> 4)*8;
        *(bf16x8*)(Vbf + ((size_t)bh*NT + token)*HD + d) = pk;
      }
    }
  }
}

__global__ __launch_bounds__(256, 3) void k_attn8(const unsigned short* __restrict__ Qbf,
    const unsigned short* __restrict__ Kbf, float* __restrict__ wsum) {
  __shared__ float l_tmp[2][64];
  __shared__ float rl[2][16];
  int bh = blockIdx.x & 127, pg = blockIdx.x >> 7;
  int t = threadIdx.x, w = t >> 6, ln = t & 63;
  int ntA = pg*2;
  bool hasB = (ntA + 1) < NTILE;
  int ntB = hasB ? (ntA + 1) : ntA;
  const unsigned short* QbA = Qbf + ((size_t)bh*NTILE + ntA)*1024;
  const unsigned short* QbB = Qbf + ((size_t)bh*NTILE + ntB)*1024;
  const unsigned short* Kb = Kbf + (size_t)bh*NTILE*1024;
  bf16x8 qA0 = *(const bf16x8*)(QbA + ln*8);
  bf16x8 qA1 = *(const bf16x8*)(QbA + 512 + ln*8);
  bf16x8 qB0 = *(const bf16x8*)(QbB + ln*8);
  bf16x8 qB1 = *(const bf16x8*)(QbB + 512 + ln*8);
  f32x4 evA[13], evB[13];
  float lpA[4] = {0.f,0.f,0.f,0.f}, lpB[4] = {0.f,0.f,0.f,0.f};
  #pragma unroll
  for (int i = 0; i < 13; i++) {
    int mt = w + 4*i;
    bool valid = (i < 12) || (w == 0);
    int mtc = valid ? mt : 48;
    bf16x8 k0 = *(const bf16x8*)(Kb + (size_t)mtc*1024 + ln*8);
    bf16x8 k1 = *(const bf16x8*)(Kb + (size_t)mtc*1024 + 512 + ln*8);
    f32x4 a = {0.f,0.f,0.f,0.f};
    a = __builtin_amdgcn_mfma_f32_16x16x32_bf16(qA0, k0, a, 0,0,0);
    a = __builtin_amdgcn_mfma_f32_16x16x32_bf16(qA1, k1, a, 0,0,0);
    f32x4 c = {0.f,0.f,0.f,0.f};
    c = __builtin_amdgcn_mfma_f32_16x16x32_bf16(qB0, k0, c, 0,0,0);
    c = __builtin_amdgcn_mfma_f32_16x16x32_bf16(qB1, k1, c, 0,0,0);
    f32x4 ea, eb;
    #pragma unroll
    for (int r = 0; r < 4; r++) {
      ea[r] = __expf(a[r]*0.125f);
      eb[r] = __expf(c[r]*0.125f);
    }
    evA[i] = ea; evB[i] = eb;
    if (valid) {
      #pragma unroll
      for (int r = 0; r < 4; r++) { lpA[r] += ea[r]; lpB[r] += eb[r]; }
    }
  }
  #pragma unroll
  for (int r = 0; r < 4; r++) {
    float v = lpA[r];
    v += __shfl_xor(v,1,64); v += __shfl_xor(v,2,64);
    v += __shfl_xor(v,4,64); v += __shfl_xor(v,8,64);
    if ((ln & 15) == 0) l_tmp[0][w*16 + (ln>>4)*4 + r] = v;
    float u = lpB[r];
    u += __shfl_xor(u,1,64); u += __shfl_xor(u,2,64);
    u += __shfl_xor(u,4,64); u += __shfl_xor(u,8,64);
    if ((ln & 15) == 0) l_tmp[1][w*16 + (ln>>4)*4 + r] = u;
  }
  __syncthreads();
  if (t < 32) {
    int g = t >> 4, q = t & 15;
    rl[g][q] = 1.f / (l_tmp[g][q] + l_tmp[g][16+q] + l_tmp[g][32+q] + l_tmp[g][48+q]);
  }
  __syncthreads();
  f32x4 rlA = *(const f32x4*)&rl[0][(ln >> 4)*4];
  f32x4 rlB = *(const f32x4*)&rl[1][(ln >> 4)*4];
  #pragma unroll
  for (int i = 0; i < 13; i++) {
    int mt = w + 4*i;
    bool valid = (i < 12) || (w == 0);
    float v = evA[i][0]*rlA[0] + evA[i][1]*rlA[1] + evA[i][2]*rlA[2] + evA[i][3]*rlA[3];
    if (hasB)
      v += evB[i][0]*rlB[0] + evB[i][1]*rlB[1] + evB[i][2]*rlB[2] + evB[i][3]*rlB[3];
    v += __shfl_xor(v, 16, 64);
    v += __shfl_xor(v, 32, 64);
    if (valid && ln < 16)
      atomicAdd(&wsum[bh*NT + mt*16 + ln], v);
  }
}

__global__ void k_attn_av(const float* __restrict__ w, const unsigned short* __restrict__ Vm,
                          float* __restrict__ abar) {
  __shared__ float red[256];
  int bh = blockIdx.x, t = threadIdx.x;
  int d = t & 63, chunk = t >> 6;
  float acc = 0.f;
  const unsigned short* vb = Vm + (size_t)bh*NT*HD;
  const float* wb = w + bh*NT;
  for (int m = chunk*196; m < (chunk+1)*196; m++)
    acc += wb[m] * bf2f(vb[(size_t)m*HD + d]);
  red[t] = acc;
  __syncthreads();
  if (t < 64)
    abar[bh*HD + t] = (red[t] + red[64+t] + red[128+t] + red[192+t]) * (1.f/NT);
}

__global__ void k_headA(const float* __restrict__ p1, const float* __restrict__ abar,
                        const float* __restrict__ wo, const float* __restrict__ bo,
                        float* __restrict__ pv) {
  int b = blockIdx.x, cg = blockIdx.y;
  int t = threadIdx.x, w = t >> 6, ln = t & 63;
  float a[8];
  #pragma unroll
  for (int k = 0; k < 8; k++) a[k] = abar[b*CC + ln + 64*k];
  int c0 = cg*32 + w*8;
  for (int i = 0; i < 8; i++) {
    int c = c0 + i;
    const float* wr = wo + (size_t)c*CC;
    float s = 0.f;
    #pragma unroll
    for (int k = 0; k < 8; k++) s += a[k] * wr[ln + 64*k];
    for (int o = 32; o; o >>= 1) s += __shfl_down(s, o, 64);
    if (ln == 0) pv[b*CC + c] = s + bo[c] + p1[b*CC + c] * (1.f/HW);
  }
}

__global__ void k_headC(const float* __restrict__ pv, const float* __restrict__ ln_g,
                        const float* __restrict__ ln_b, const float* __restrict__ fc1_w,
                        const float* __restrict__ fc1_b, const float* __restrict__ fc2_w,
                        const float* __restrict__ fc2_b, float* __restrict__ out) {
  int b = blockIdx.x, cg = blockIdx.y;
  int t = threadIdx.x, w = t >> 6, ln = t & 63;
  float a[8];
  float s = 0.f, s2 = 0.f;
  #pragma unroll
  for (int k = 0; k < 8; k++) {
    a[k] = pv[b*CC + ln + 64*k];
    s += a[k]; s2 += a[k]*a[k];
  }
  for (int o = 32; o; o >>= 1) { s += __shfl_down(s, o, 64); s2 += __shfl_down(s2, o, 64); }
  s = __shfl(s, 0, 64); s2 = __shfl(s2, 0, 64);
  float mean = s * (1.f/CC);
  float rs = rsqrtf(s2*(1.f/CC) - mean*mean + 1e-5f);
  #pragma unroll
  for (int k = 0; k < 8; k++)
    a[k] = (a[k]-mean)*rs*ln_g[ln + 64*k] + ln_b[ln + 64*k];
  int c0 = cg*32 + w*8;
  float o2 = 0.f;
  for (int i = 0; i < 8; i++) {
    int c = c0 + i;
    const float* wr = fc1_w + (size_t)c*CC;
    float v = 0.f;
    #pragma unroll
    for (int k = 0; k < 8; k++) v += a[k] * wr[ln + 64*k];
    for (int o = 32; o; o >>= 1) v += __shfl_down(v, o, 64);
    if (ln == 0) o2 += fmaxf(v + fc1_b[c], 0.f) * fc2_w[c];
  }
  if (ln == 0) {
    if (cg == 0 && w == 0) o2 += fc2_b[0];
    atomicAdd(&out[b], o2);
  }
}

extern "C" void kernel_launch(void* const* d_in, const int* in_sizes, int n_in,
                              void* d_out, int out_size, void* d_ws, size_t ws_size,
                              hipStream_t stream) {
  const float* x       = (const float*)d_in[0];
  const float* mlp_w1  = (const float*)d_in[1];
  const float* mlp_b1  = (const float*)d_in[2];
  const float* mlp_w2  = (const float*)d_in[3];
  const float* mlp_b2  = (const float*)d_in[4];
  const float* sp_w    = (const float*)d_in[5];
  const float* sp_g    = (const float*)d_in[6];
  const float* sp_b    = (const float*)d_in[7];
  const float* sp_mu   = (const float*)d_in[8];
  const float* sp_var  = (const float*)d_in[9];
  const float* wq      = (const float*)d_in[10];
  const float* bq      = (const float*)d_in[11];
  const float* wk      = (const float*)d_in[12];
  const float* bk      = (const float*)d_in[13];
  const float* wv      = (const float*)d_in[14];
  const float* bv      = (const float*)d_in[15];
  const float* wo      = (const float*)d_in[16];
  const float* bo      = (const float*)d_in[17];
  const float* ln_g    = (const float*)d_in[18];
  const float* ln_b    = (const float*)d_in[19];
  const float* fc1_w   = (const float*)d_in[20];
  const float* fc1_b   = (const float*)d_in[21];
  const float* fc2_w   = (const float*)d_in[22];
  const float* fc2_b   = (const float*)d_in[23];

  float* ws = (float*)d_ws;
  float* avg_p = ws + OFS_AVGP;
  float* max_p = ws + OFS_MAXP;
  float* chs   = ws + OFS_CHS;
  float* sp    = ws + OFS_SP;
  float* p1    = ws + OFS_P1;
  float* abar  = ws + OFS_ABAR;
  unsigned short* xgT = (unsigned short*)(ws + OFS_XGT);
  unsigned short* Qbf = (unsigned short*)(ws + OFS_QBF);
  unsigned short* Kbf = (unsigned short*)(ws + OFS_KBF);
  unsigned short* Vbf = (unsigned short*)(ws + OFS_V2);
  unsigned short* Wf  = (unsigned short*)(ws + OFS_WF);
  float* wsum  = ws + OFS_W;
  float* pv    = ws + OFS_PV;
  float* cmaxp = ws + OFS_CMAXP;
  float* cmeanp= ws + OFS_CMEANP;

  // occupancy-derived cooperative grid (computed once)
  static int coopGrid = -2;
  if (coopGrid == -2) {
    int nb = 0;
    if (hipOccupancyMaxActiveBlocksPerMultiprocessor(&nb, k_mega, 256, 0) != hipSuccess)
      nb = 0;
    coopGrid = (nb >= 1) ? (nb > 2 ? 2 : nb) * 256 : -1;   // cap at 512 blocks
  }

  bool ok = false;
  if (coopGrid > 0) {
    MegaArgs A;
    A.x = x; A.mlp_w1 = mlp_w1; A.mlp_b1 = mlp_b1; A.mlp_w2 = mlp_w2; A.mlp_b2 = mlp_b2;
    A.sp_w = sp_w; A.sp_g = sp_g; A.sp_bb = sp_b; A.sp_mu = sp_mu; A.sp_var = sp_var;
    A.wq = wq; A.bq = bq; A.wk = wk; A.bk = bk; A.wv = wv; A.bv = bv; A.wo = wo; A.bo = bo;
    A.ln_g = ln_g; A.ln_b = ln_b; A.fc1_w = fc1_w; A.fc1_b = fc1_b; A.fc2_w = fc2_w; A.fc2_b = fc2_b;
    A.avg_p = avg_p; A.max_p = max_p; A.chs = chs; A.sp = sp; A.p1 = p1; A.abar = abar;
    A.wsum = wsum; A.pv = pv; A.out = (float*)d_out;
    A.cmaxp = cmaxp; A.cmeanp = cmeanp;
    A.xgT = xgT; A.Qbf = Qbf; A.Kbf = Kbf; A.Vbf = Vbf; A.Wf = Wf;
    void* kargs[] = { (void*)&A };
    hipError_t e = hipLaunchCooperativeKernel((const void*)k_mega, dim3(coopGrid),
                                              dim3(256), kargs, 0, stream);
    ok = (e == hipSuccess);
    if (!ok) coopGrid = -1;                       // don't retry next call
  }

  if (!ok) {
    // fallback: verified 10-kernel pipeline (round 3)
    k_pre    <<<2496, 256, 0, stream>>>(x, wq, wk, wv, avg_p, max_p, Wf, wsum, p1,
                                        (float*)d_out);
    k_chmlp  <<<BB, 256, 0, stream>>>(avg_p, max_p, mlp_w1, mlp_b1, mlp_w2, mlp_b2, chs);
    k_chgatep<<<dim3(BB,16), 256, 0, stream>>>(x, chs, cmaxp, cmeanp);
    k_credsp <<<dim3(BB,4), 256, 0, stream>>>(cmaxp, cmeanp, sp_w, sp_g, sp_b, sp_mu, sp_var, sp);
    k_sfuse  <<<dim3(NTILE,BB), 256, 0, stream>>>(x, chs, sp, xgT, p1);
    k_qkv_mfma<<<1248, 256, 0, stream>>>(xgT, Wf, bq, bk, bv, Qbf, Kbf, Vbf);
    k_attn8  <<<25*128, 256, 0, stream>>>(Qbf, Kbf, wsum);
    k_attn_av<<<128, 256, 0, stream>>>(wsum, Vbf, abar);
    k_headA  <<<dim3(BB,16), 256, 0, stream>>>(p1, abar, wo, bo, pv);
    k_headC  <<<dim3(BB,16), 256, 0, stream>>>(pv, ln_g, ln_b, fc1_w, fc1_b,
                                               fc2_w, fc2_b, (float*)d_out);
  }
}